// Round 11
// baseline (535.554 us; speedup 1.0000x reference)
//
#include <hip/hip_runtime.h>
#include <math.h>

namespace {

typedef __attribute__((ext_vector_type(8))) short bf16x8;
typedef __attribute__((ext_vector_type(4))) float f32x4;

constexpr int NCg = 128;

// ---- scalar helpers ----
__device__ inline short bfr(float f) {            // fp32 -> bf16 RNE
    unsigned u = __float_as_uint(f);
    unsigned r = (u + 0x7fffu + ((u >> 16) & 1u)) >> 16;
    return (short)r;
}
__device__ inline float bf2f(short s) {
    return __uint_as_float(((unsigned)(unsigned short)s) << 16);
}
__device__ inline unsigned pack2(float a, float b) {
    return (unsigned)(unsigned short)bfr(a) | ((unsigned)(unsigned short)bfr(b) << 16);
}
__device__ inline float tanh_f(float x) {         // 1 - 2/(e^{2x}+1)
    float t = __builtin_amdgcn_exp2f(x * 2.8853900817779268f);
    return 1.0f - 2.0f * __builtin_amdgcn_rcpf(t + 1.0f);
}
__device__ inline float sig05(float x) { return 0.5f / (1.0f + expf(-x)); }

// ---- swizzled LDS accessors (byte ^= (row&7)<<4) ----
__device__ inline float* hptr(float* base, int i, int d) {          // fp32 [64][64]
    int byte = (i << 8) + (d << 2); byte ^= (i & 7) << 4;
    return (float*)((char*)base + byte);
}
__device__ inline bf16x8 ld64(const short* base, int row, int kbyte) {   // bf16 pitch 64
    int byte = (row << 7) + kbyte; byte ^= (row & 7) << 4;
    return *(const bf16x8*)((const char*)base + byte);
}
__device__ inline bf16x8 ld128(const short* base, int row, int kbyte) {  // bf16 pitch 128
    int byte = (row << 8) + kbyte; byte ^= (row & 7) << 4;
    return *(const bf16x8*)((const char*)base + byte);
}
__device__ inline short* p16_64(short* base, int row, int col) {
    int byte = (row << 7) + (col << 1); byte ^= (row & 7) << 4;
    return (short*)((char*)base + byte);
}
__device__ inline void st32_64(short* base, int row, int col, unsigned v) { // col even
    int byte = (row << 7) + (col << 1); byte ^= (row & 7) << 4;
    *(unsigned*)((char*)base + byte) = v;
}
__device__ inline void st32_128(short* base, int row, int col, unsigned v) { // col even
    int byte = (row << 8) + (col << 1); byte ^= (row & 7) << 4;
    *(unsigned*)((char*)base + byte) = v;
}
#define MFMA(a,b,c) __builtin_amdgcn_mfma_f32_16x16x32_bf16(a, b, c, 0, 0, 0)
#define PIN(v) asm volatile("" : "+v"(v))

// init: w2 [64][128] and w1 [128][64] fp32 -> bf16 tables in ws
__global__ void cvt_w12(const float* __restrict__ w2, const float* __restrict__ w1,
                        short* __restrict__ w2b, short* __restrict__ w1b) {
    int e = blockIdx.x * 256 + threadIdx.x;   // 64 blocks -> 16384
    if (e < 8192) w2b[e] = bfr(w2[e]);
    else          w1b[e - 8192] = bfr(w1[e - 8192]);
}

// init: per-lane A-fragment W0 table, per-lane nb table, sigmoid gate tables
__global__ __launch_bounds__(256) void build_tables(
    const float* __restrict__ W0,    // [1024][64][64]
    const float* __restrict__ nid,   // [128][64][64]
    const float* __restrict__ b2,    // [64]
    const float* __restrict__ dgl,   // [128][64]
    const float* __restrict__ hdl,   // [128][64]
    short* __restrict__ w0t,         // [1024][256][16] bf16
    short* __restrict__ nbt,         // [128][256][16] bf16
    float* __restrict__ gt,          // [128][64]
    float* __restrict__ hgt)         // [128][64]
{
    const int bc  = blockIdx.x;      // 1024
    const int tid = threadIdx.x;
    const int Wv = tid >> 6, l = tid & 63, g = l >> 4, lm = l & 15;
    const int rowA = 16 * Wv + lm;
    const int rowC = 16 * Wv + 4 * g;
    {   // w0t: lane's two A-fragment k-slices of W0[bc]
        const float* w0row = W0 + (size_t)bc * 4096 + (size_t)rowA * 64;
        short* dst = w0t + ((size_t)bc * 256 + tid) * 16;
        #pragma unroll
        for (int jj = 0; jj < 8; ++jj) {
            dst[jj]     = bfr(w0row[8 * g + jj]);
            dst[8 + jj] = bfr(w0row[32 + 8 * g + jj]);
        }
    }
    if (bc < 128) {
        const int c = bc;
        short* dst = nbt + ((size_t)c * 256 + tid) * 16;
        #pragma unroll
        for (int nt = 0; nt < 4; ++nt) {
            int d = lm + 16 * nt;
            #pragma unroll
            for (int r = 0; r < 4; ++r)
                dst[nt * 4 + r] = bfr(b2[d] + nid[((size_t)c * 64 + rowC + r) * 64 + d]);
        }
        if (tid < 64) {
            gt [c * 64 + tid] = sig05(dgl[c * 64 + tid]);
            hgt[c * 64 + tid] = sig05(hdl[c * 64 + tid]);
        }
    }
}

// init: inj[bt,c,p] = injb[c,p] + x[bt,c,:] . injw[c,p,:]   (exact fp32)
__global__ __launch_bounds__(256) void inj_gemm(
    const float* __restrict__ x,     // [128 bt][128 c][64]
    const float* __restrict__ injw,  // [c][256][64]
    const float* __restrict__ injb,  // [c][256]
    float* __restrict__ inj)         // [bt][c][256]
{
    const int c = blockIdx.x;        // 128
    const int p = threadIdx.x;       // 256
    float w[64];
    const float* wr = injw + ((size_t)c * 256 + p) * 64;
    #pragma unroll
    for (int k = 0; k < 64; k += 4) {
        float4 v = *(const float4*)(wr + k);
        w[k] = v.x; w[k+1] = v.y; w[k+2] = v.z; w[k+3] = v.w;
    }
    const float bias = injb[c * 256 + p];
    __shared__ float xs[16][64];
    #pragma unroll 1
    for (int chunk = 0; chunk < 8; ++chunk) {
        const int bt0 = chunk * 16;
        {
            int e = threadIdx.x * 4;
            *(float4*)&xs[e >> 6][e & 63] =
                *(const float4*)(x + ((size_t)(bt0 + (e >> 6)) * NCg + c) * 64 + (e & 63));
        }
        __syncthreads();
        #pragma unroll 1
        for (int r = 0; r < 16; ++r) {
            float acc = bias;
            #pragma unroll
            for (int k = 0; k < 64; ++k) acc = fmaf(w[k], xs[r][k], acc);
            inj[((size_t)(bt0 + r) * NCg + c) * 256 + p] = acc;
        }
        __syncthreads();
    }
}

__global__ __launch_bounds__(256, 4) void memgraph_mfma(
    const float* __restrict__ inj,    const float* __restrict__ h0,
    const float* __restrict__ heb0,   const short* __restrict__ w0t,
    const short* __restrict__ nbt,    const float* __restrict__ gt,
    const float* __restrict__ hgt,    const short* __restrict__ w1b,
    const float* __restrict__ b1,     const short* __restrict__ w2b,
    const float* __restrict__ wdl,
    const int*  __restrict__ iport,   const int*  __restrict__ oport,
    float* __restrict__ out)
{
    __shared__ float h_s[64 * 64];                                   // 16384 B
    __shared__ short heb_s[64 * 64];                                 //  8192 B
    __shared__ short arena[8192] __attribute__((aligned(16)));       // 16384 B
    // total 40960 B -> exactly 4 blocks/CU; grid 1024 = one resident round

    short* m1A  = arena;              // S0: m1 [i][k]      (post-P2)
    short* hinT = arena + 4096;       // S1: h_in^T [d][j]  (rebuilt each step in P5)
    short* hidA = arena;              // S0+S1: hid [i][hh] pitch 128 (post-P3a)
    short* hnA  = arena;              // S0: h_new [i][d]   (post-P5)

    const int bc  = blockIdx.x;
    const int b   = bc >> 7;
    const int c   = bc & (NCg - 1);
    const int tid = threadIdx.x;
    const int Wv  = tid >> 6;          // wave 0..3
    const int l   = tid & 63;
    const int g   = l >> 4;
    const int lm  = l & 15;
    const int rowC = 16 * Wv + 4 * g;  // C-frag row base (+reg r)
    const int rowA = 16 * Wv + lm;     // A-frag row
    const int kb0  = 16 * g;           // fragment k-byte base

    const size_t cellBase = (size_t)bc;

    // ---- stage state ----
    const float* h0p  = h0   + cellBase * 4096;
    const float* hb0p = heb0 + cellBase * 4096;
    #pragma unroll
    for (int u = 0; u < 16; ++u) {
        int e = tid + 256 * u;
        *hptr(h_s, e >> 6, e & 63)     = h0p[e];
        *p16_64(heb_s, e >> 6, e & 63) = bfr(hb0p[e]);
    }

    // ---- private t-invariants: 17 packed regs (w0 frag 8, nb 8, wdec 1) ----
    float wdecA = 1.0f - sig05(wdl[c * 64 + rowA]);
    float wpowA = 1.0f;
    unsigned w0q[8], nbq[8];
    {
        const unsigned* wp = (const unsigned*)(w0t + ((size_t)bc * 256 + tid) * 16);
        const unsigned* np = (const unsigned*)(nbt + ((size_t)c  * 256 + tid) * 16);
        #pragma unroll
        for (int k = 0; k < 8; ++k) { w0q[k] = wp[k]; nbq[k] = np[k]; }
    }
    PIN(wdecA);
    #pragma unroll
    for (int k = 0; k < 8; ++k) { PIN(w0q[k]); PIN(nbq[k]); }

    // shared streams stay per-step (L2-resident now that private churn is gone)
    const float* gp  = gt  + c * 64 + rowC;
    const float* hgp = hgt + c * 64 + rowC;

    const int dn = l;
    int ip4[4], op4[4];
    #pragma unroll
    for (int a = 0; a < 4; ++a) { ip4[a] = iport[c * 4 + a]; op4[a] = oport[c * 4 + a]; }
    const int pin = ip4[Wv];
    const bool own = !((Wv > 0 && ip4[0] == pin) ||
                       (Wv > 1 && ip4[1] == pin) ||
                       (Wv > 2 && ip4[2] == pin));

    // inj prefetch for t=0
    float injv[4];
    {
        const float* ir = inj + (((size_t)b * 16) * NCg + c) * 256 + dn;
        #pragma unroll
        for (int a = 0; a < 4; ++a) injv[a] = ir[a * 64];
    }

    __syncthreads();

    // ---- prologue: hinT = h^T (bf16) ----
    {
        int d = tid >> 2, q = tid & 3;
        #pragma unroll
        for (int k = 0; k < 16; k += 2) {
            int col = 16 * q + k;
            st32_64(hinT, d, col, pack2(*hptr(h_s, col, d), *hptr(h_s, col + 1, d)));
        }
    }
    __syncthreads();

    const f32x4 zf = {0.f, 0.f, 0.f, 0.f};

    #pragma unroll 1
    for (int t = 0; t < 16; ++t) {
        int go = 0; asm volatile("" : "+v"(go));   // launder: keep shared streams per-step

        // ==== P1: scatter (owner wave per distinct port; plain stores) ====
        if (own) {
            float v = 0.0f;
            #pragma unroll
            for (int a = 0; a < 4; ++a)
                if (ip4[a] == pin) v += injv[a];     // wave-uniform branch
            float hv = *hptr(h_s, pin, dn) + v;
            *hptr(h_s, pin, dn) = hv;
            *p16_64(hinT, dn, pin) = bfr(hv);
        }
        __syncthreads();                                           // B1

        // ==== P2: m1 = (wpow*W0 + heb) @ h_in ; A from reg W0 + LDS heb ====
        f32x4 acc2[4] = {zf, zf, zf, zf};
        {
            bf16x8 hb0 = ld64(heb_s, rowA, kb0);
            bf16x8 hb1 = ld64(heb_s, rowA, kb0 + 64);
            bf16x8 a0, a1;
            #pragma unroll
            for (int jj = 0; jj < 8; ++jj) {
                float w0lo = bf2f((short)(w0q[jj >> 1]       >> (16 * (jj & 1))));
                float w0hi = bf2f((short)(w0q[4 + (jj >> 1)] >> (16 * (jj & 1))));
                a0[jj] = bfr(fmaf(wpowA, w0lo, bf2f(hb0[jj])));
                a1[jj] = bfr(fmaf(wpowA, w0hi, bf2f(hb1[jj])));
            }
            #pragma unroll
            for (int nt = 0; nt < 4; ++nt) {
                bf16x8 bb0 = ld64(hinT, lm + 16 * nt, kb0);
                bf16x8 bb1 = ld64(hinT, lm + 16 * nt, kb0 + 64);
                acc2[nt] = MFMA(a0, bb0, acc2[nt]);
                acc2[nt] = MFMA(a1, bb1, acc2[nt]);
            }
        }
        #pragma unroll
        for (int nt = 0; nt < 4; ++nt)
            #pragma unroll
            for (int r = 0; r < 4; ++r)
                *p16_64(m1A, rowC + r, lm + 16 * nt) = bfr(acc2[nt][r]);
        __syncthreads();                                           // B4 (m1 handoff)

        // prefetch inj for next step
        {
            int tn = (t < 15) ? t + 1 : 15;
            const float* ir = inj + (((size_t)(b * 16 + tn)) * NCg + c) * 256 + dn;
            #pragma unroll
            for (int a = 0; a < 4; ++a) injv[a] = ir[a * 64];
        }

        // ==== P3a: hid = tanh(w1 @ m1^T + b1); pack BEFORE barrier ====
        unsigned pk[16];
        #pragma unroll
        for (int mt = 0; mt < 2; ++mt) {
            bf16x8 awf0 = *(const bf16x8*)(w1b + ((32 * Wv + 16 * mt + lm) << 6) + 8 * g + go);
            bf16x8 awf1 = *(const bf16x8*)(w1b + ((32 * Wv + 16 * mt + lm) << 6) + 8 * g + 32 + go);
            float4 b1f = *(const float4*)(b1 + 32 * Wv + 16 * mt + 4 * g + go);
            float b1a[4] = {b1f.x, b1f.y, b1f.z, b1f.w};
            #pragma unroll
            for (int nt = 0; nt < 4; ++nt) {
                f32x4 a3 = zf;
                a3 = MFMA(awf0, ld64(m1A, lm + 16 * nt, kb0),      a3);
                a3 = MFMA(awf1, ld64(m1A, lm + 16 * nt, kb0 + 64), a3);
                float v0 = tanh_f(a3[0] + b1a[0]);
                float v1 = tanh_f(a3[1] + b1a[1]);
                float v2 = tanh_f(a3[2] + b1a[2]);
                float v3 = tanh_f(a3[3] + b1a[3]);
                pk[(mt * 4 + nt) * 2 + 0] = pack2(v0, v1);
                pk[(mt * 4 + nt) * 2 + 1] = pack2(v2, v3);
            }
        }
        __syncthreads();                                           // B5 (all m1A reads done)
        #pragma unroll
        for (int mt = 0; mt < 2; ++mt)
            #pragma unroll
            for (int nt = 0; nt < 4; ++nt) {
                st32_128(hidA, lm + 16 * nt, 32 * Wv + 16 * mt + 4 * g + 0, pk[(mt * 4 + nt) * 2 + 0]);
                st32_128(hidA, lm + 16 * nt, 32 * Wv + 16 * mt + 4 * g + 2, pk[(mt * 4 + nt) * 2 + 1]);
            }
        __syncthreads();                                           // B6 (hid handoff)

        // ==== P3b: m2 = hid @ w2^T  (w2b L2-hot stream) ====
        f32x4 accB[4] = {zf, zf, zf, zf};
        {
            bf16x8 ah[4];
            #pragma unroll
            for (int kt = 0; kt < 4; ++kt)
                ah[kt] = ld128(hidA, 16 * Wv + lm, kb0 + 64 * kt);
            #pragma unroll
            for (int kt = 0; kt < 4; ++kt)
                #pragma unroll
                for (int nt = 0; nt < 4; ++nt) {
                    const short* w2r = w2b + ((lm + 16 * nt) << 7) + 8 * g + 32 * kt + go;
                    bf16x8 bb = *(const bf16x8*)w2r;
                    accB[nt] = MFMA(ah[kt], bb, accB[nt]);
                }
        }
        __syncthreads();                                           // B7 (hidA dead)

        // ==== P5: gated state update; nb from regs, gi stream ====
        {
            float4 gf = *(const float4*)(gp + go);
            float giv[4] = {gf.x, gf.y, gf.z, gf.w};
            #pragma unroll
            for (int nt = 0; nt < 4; ++nt) {
                int d = lm + 16 * nt;
                float hv[4];
                #pragma unroll
                for (int r = 0; r < 4; ++r) {
                    int i = rowC + r;
                    float nb = bf2f((short)(nbq[nt * 2 + (r >> 1)] >> (16 * (r & 1))));
                    float hin = *hptr(h_s, i, d);
                    float tv  = tanh_f(accB[nt][r] + nb);
                    hv[r] = (1.0f - giv[r]) * hin + giv[r] * tv;
                    *hptr(h_s, i, d) = hv[r];
                    *p16_64(hnA, i, d) = bfr(hv[r]);
                }
                st32_64(hinT, d, rowC,     pack2(hv[0], hv[1]));
                st32_64(hinT, d, rowC + 2, pack2(hv[2], hv[3]));
            }
        }
        __syncthreads();                                           // B8 (h_new handoff)

        // ==== P6: hebbian outer product + readout; stream hg (f32) ====
        f32x4 acc6[4] = {zf, zf, zf, zf};
        {
            bf16x8 ha0 = ld64(hnA, rowA, kb0);
            bf16x8 ha1 = ld64(hnA, rowA, kb0 + 64);
            #pragma unroll
            for (int nt = 0; nt < 4; ++nt) {
                bf16x8 bb0 = ld64(hnA, lm + 16 * nt, kb0);
                bf16x8 bb1 = ld64(hnA, lm + 16 * nt, kb0 + 64);
                acc6[nt] = MFMA(ha0, bb0, acc6[nt]);
                acc6[nt] = MFMA(ha1, bb1, acc6[nt]);
            }
        }
        if (tid < 64) {   // readout of h_new (stable during P6)
            float ro = 0.125f * (*hptr(h_s, op4[0], tid) + *hptr(h_s, op4[1], tid) +
                                 *hptr(h_s, op4[2], tid) + *hptr(h_s, op4[3], tid));
            out[(((size_t)b * 16 + t) * NCg + c) * 64 + tid] = ro;
        }
        {
            float4 hf = *(const float4*)(hgp + go);
            float hgv[4] = {hf.x, hf.y, hf.z, hf.w};
            #pragma unroll
            for (int nt = 0; nt < 4; ++nt)
                #pragma unroll
                for (int r = 0; r < 4; ++r) {
                    int i = rowC + r, j = lm + 16 * nt;
                    short* hb = p16_64(heb_s, i, j);
                    float nv = (1.0f - hgv[r]) * bf2f(*hb) + hgv[r] * (acc6[nt][r] * 0.015625f);
                    *hb = (j == i) ? (short)0 : bfr(nv);
                }
        }
        wpowA *= wdecA;
        __syncthreads();                                           // B9 (protect h_s/heb/hinT)
    }
}

} // namespace

extern "C" void kernel_launch(void* const* d_in, const int* in_sizes, int n_in,
                              void* d_out, int out_size, void* d_ws, size_t ws_size,
                              hipStream_t stream) {
    (void)in_sizes; (void)n_in; (void)out_size; (void)ws_size;
    const float* x    = (const float*)d_in[0];
    const float* h0   = (const float*)d_in[1];
    const float* W0   = (const float*)d_in[2];
    const float* heb0 = (const float*)d_in[3];
    const float* nid  = (const float*)d_in[4];
    const float* w1   = (const float*)d_in[5];
    const float* b1   = (const float*)d_in[6];
    const float* w2   = (const float*)d_in[7];
    const float* b2   = (const float*)d_in[8];
    const float* injw = (const float*)d_in[9];
    const float* injb = (const float*)d_in[10];
    const float* wdl  = (const float*)d_in[11];
    const float* dgl  = (const float*)d_in[12];
    const float* hdl  = (const float*)d_in[13];
    const int*   ip   = (const int*)d_in[14];
    const int*   op   = (const int*)d_in[15];
    float* out = (float*)d_out;

    char* ws = (char*)d_ws;
    short* w2b = (short*)(ws + 0);              // 16 KB
    short* w1b = (short*)(ws + 16384);          // 16 KB
    float* gt  = (float*)(ws + 32768);          // 32 KB
    float* hgt = (float*)(ws + 65536);          // 32 KB
    short* nbt = (short*)(ws + 98304);          // 1 MB
    short* w0t = (short*)(ws + 1146880);        // 8 MB
    float* inj = (float*)(ws + 9535488);        // 16 MB

    cvt_w12<<<dim3(64), dim3(256), 0, stream>>>(w2, w1, w2b, w1b);
    build_tables<<<dim3(1024), dim3(256), 0, stream>>>(W0, nid, b2, dgl, hdl,
                                                       w0t, nbt, gt, hgt);
    inj_gemm<<<dim3(128), dim3(256), 0, stream>>>(x, injw, injb, inj);
    memgraph_mfma<<<dim3(8 * NCg), dim3(256), 0, stream>>>(
        inj, h0, heb0, w0t, nbt, gt, hgt, w1b, b1, w2b,
        wdl, ip, op, out);
}

// Round 12
// 509.728 us; speedup vs baseline: 1.0507x; 1.0507x over previous
//
#include <hip/hip_runtime.h>
#include <math.h>

namespace {

typedef __attribute__((ext_vector_type(8))) short bf16x8;
typedef __attribute__((ext_vector_type(4))) float f32x4;

constexpr int NCg = 128;

// ---- scalar helpers ----
__device__ inline short bfr(float f) {            // fp32 -> bf16 RNE
    unsigned u = __float_as_uint(f);
    unsigned r = (u + 0x7fffu + ((u >> 16) & 1u)) >> 16;
    return (short)r;
}
__device__ inline float bf2f(short s) {
    return __uint_as_float(((unsigned)(unsigned short)s) << 16);
}
__device__ inline unsigned pack2(float a, float b) {
    return (unsigned)(unsigned short)bfr(a) | ((unsigned)(unsigned short)bfr(b) << 16);
}
__device__ inline float tanh_f(float x) {         // 1 - 2/(e^{2x}+1)
    float t = __builtin_amdgcn_exp2f(x * 2.8853900817779268f);
    return 1.0f - 2.0f * __builtin_amdgcn_rcpf(t + 1.0f);
}
__device__ inline float sig05(float x) { return 0.5f / (1.0f + expf(-x)); }

// ---- swizzled LDS accessors (byte ^= (row&7)<<4) ----
__device__ inline bf16x8 ld64(const short* base, int row, int kbyte) {   // bf16 pitch 64
    int byte = (row << 7) + kbyte; byte ^= (row & 7) << 4;
    return *(const bf16x8*)((const char*)base + byte);
}
__device__ inline bf16x8 ld128(const short* base, int row, int kbyte) {  // bf16 pitch 128
    int byte = (row << 8) + kbyte; byte ^= (row & 7) << 4;
    return *(const bf16x8*)((const char*)base + byte);
}
__device__ inline short* p16_64(short* base, int row, int col) {
    int byte = (row << 7) + (col << 1); byte ^= (row & 7) << 4;
    return (short*)((char*)base + byte);
}
__device__ inline void st32_64(short* base, int row, int col, unsigned v) { // col even
    int byte = (row << 7) + (col << 1); byte ^= (row & 7) << 4;
    *(unsigned*)((char*)base + byte) = v;
}
__device__ inline void st32_128(short* base, int row, int col, unsigned v) { // col even
    int byte = (row << 8) + (col << 1); byte ^= (row & 7) << 4;
    *(unsigned*)((char*)base + byte) = v;
}
#define MFMA(a,b,c) __builtin_amdgcn_mfma_f32_16x16x32_bf16(a, b, c, 0, 0, 0)
#define PIN(v) asm volatile("" : "+v"(v))

// init: w2 [64][128] and w1 [128][64] fp32 -> bf16 tables in ws
__global__ void cvt_w12(const float* __restrict__ w2, const float* __restrict__ w1,
                        short* __restrict__ w2b, short* __restrict__ w1b) {
    int e = blockIdx.x * 256 + threadIdx.x;   // 64 blocks -> 16384
    if (e < 8192) w2b[e] = bfr(w2[e]);
    else          w1b[e - 8192] = bfr(w1[e - 8192]);
}

// init: per-lane A-fragment W0 table, per-lane nb table, sigmoid gate tables
__global__ __launch_bounds__(256) void build_tables(
    const float* __restrict__ W0,    // [1024][64][64]
    const float* __restrict__ nid,   // [128][64][64]
    const float* __restrict__ b2,    // [64]
    const float* __restrict__ dgl,   // [128][64]
    const float* __restrict__ hdl,   // [128][64]
    short* __restrict__ w0t,         // [1024][256][16] bf16
    short* __restrict__ nbt,         // [128][256][16] bf16
    float* __restrict__ gt,          // [128][64]
    float* __restrict__ hgt)         // [128][64]
{
    const int bc  = blockIdx.x;      // 1024
    const int tid = threadIdx.x;
    const int Wv = tid >> 6, l = tid & 63, g = l >> 4, lm = l & 15;
    const int rowA = 16 * Wv + lm;
    const int rowC = 16 * Wv + 4 * g;
    {   // w0t: lane's two A-fragment k-slices of W0[bc]
        const float* w0row = W0 + (size_t)bc * 4096 + (size_t)rowA * 64;
        short* dst = w0t + ((size_t)bc * 256 + tid) * 16;
        #pragma unroll
        for (int jj = 0; jj < 8; ++jj) {
            dst[jj]     = bfr(w0row[8 * g + jj]);
            dst[8 + jj] = bfr(w0row[32 + 8 * g + jj]);
        }
    }
    if (bc < 128) {
        const int c = bc;
        short* dst = nbt + ((size_t)c * 256 + tid) * 16;
        #pragma unroll
        for (int nt = 0; nt < 4; ++nt) {
            int d = lm + 16 * nt;
            #pragma unroll
            for (int r = 0; r < 4; ++r)
                dst[nt * 4 + r] = bfr(b2[d] + nid[((size_t)c * 64 + rowC + r) * 64 + d]);
        }
        if (tid < 64) {
            gt [c * 64 + tid] = sig05(dgl[c * 64 + tid]);
            hgt[c * 64 + tid] = sig05(hdl[c * 64 + tid]);
        }
    }
}

// init: inj[bt,c,p] = injb[c,p] + x[bt,c,:] . injw[c,p,:]   (exact fp32)
__global__ __launch_bounds__(256) void inj_gemm(
    const float* __restrict__ x,     // [128 bt][128 c][64]
    const float* __restrict__ injw,  // [c][256][64]
    const float* __restrict__ injb,  // [c][256]
    float* __restrict__ inj)         // [bt][c][256]
{
    const int c = blockIdx.x;        // 128
    const int p = threadIdx.x;       // 256
    float w[64];
    const float* wr = injw + ((size_t)c * 256 + p) * 64;
    #pragma unroll
    for (int k = 0; k < 64; k += 4) {
        float4 v = *(const float4*)(wr + k);
        w[k] = v.x; w[k+1] = v.y; w[k+2] = v.z; w[k+3] = v.w;
    }
    const float bias = injb[c * 256 + p];
    __shared__ float xs[16][64];
    #pragma unroll 1
    for (int chunk = 0; chunk < 8; ++chunk) {
        const int bt0 = chunk * 16;
        {
            int e = threadIdx.x * 4;
            *(float4*)&xs[e >> 6][e & 63] =
                *(const float4*)(x + ((size_t)(bt0 + (e >> 6)) * NCg + c) * 64 + (e & 63));
        }
        __syncthreads();
        #pragma unroll 1
        for (int r = 0; r < 16; ++r) {
            float acc = bias;
            #pragma unroll
            for (int k = 0; k < 64; ++k) acc = fmaf(w[k], xs[r][k], acc);
            inj[((size_t)(bt0 + r) * NCg + c) * 256 + p] = acc;
        }
        __syncthreads();
    }
}

__global__ __launch_bounds__(256, 4) void memgraph_mfma(
    const float* __restrict__ inj,    const float* __restrict__ h0,
    const float* __restrict__ heb0,   const short* __restrict__ w0t,
    const short* __restrict__ nbt,    const float* __restrict__ gt,
    const float* __restrict__ hgt,    const short* __restrict__ w1b,
    const float* __restrict__ b1,     const short* __restrict__ w2b,
    const float* __restrict__ wdl,
    const int*  __restrict__ iport,   const int*  __restrict__ oport,
    float* __restrict__ out)
{
    __shared__ short heb_s[4096];                                 //  8 KB
    __shared__ short hinT_s[4096];                                //  8 KB  h_in^T
    __shared__ short mh_s[4096];                                  //  8 KB  m1A / hnA
    __shared__ short hidA_s[8192] __attribute__((aligned(16)));   // 16 KB  hid (pitch 128)
    // total 40960 B -> exactly 4 blocks/CU; grid 1024 = one resident round

    const int bc  = blockIdx.x;
    const int b   = bc >> 7;
    const int c   = bc & (NCg - 1);
    const int tid = threadIdx.x;
    const int Wv  = tid >> 6;          // wave 0..3
    const int l   = tid & 63;
    const int g   = l >> 4;
    const int lm  = l & 15;
    const int rowC = 16 * Wv + 4 * g;  // C-frag row base (+reg r)
    const int rowA = 16 * Wv + lm;     // A-frag row
    const int kb0  = 16 * g;           // fragment k-byte base

    const size_t cellBase = (size_t)bc;

    // ---- stage hebbian ----
    const float* hb0p = heb0 + cellBase * 4096;
    #pragma unroll
    for (int u = 0; u < 16; ++u) {
        int e = tid + 256 * u;
        *p16_64(heb_s, e >> 6, e & 63) = bfr(hb0p[e]);
    }

    float wdecA = 1.0f - sig05(wdl[c * 64 + rowA]);
    float wpowA = 1.0f;
    PIN(wdecA);

    // L2 stream bases (t-invariant)
    const short* w0p = w0t + ((size_t)bc * 256 + tid) * 16;
    const short* nbp = nbt + ((size_t)c  * 256 + tid) * 16;
    const float* gp  = gt  + c * 64 + rowC;
    const float* hgp = hgt + c * 64 + rowC;

    int ip4[4], op4[4];
    #pragma unroll
    for (int a = 0; a < 4; ++a) { ip4[a] = iport[c * 4 + a]; op4[a] = oport[c * 4 + a]; }

    // ---- h_in state in registers: hreg[nt*4+r] = h_in[rowC+r][lm+16nt] ----
    float hreg[16];
    {
        const float* h0c = h0 + cellBase * 4096;
        const float* ir0 = inj + (((size_t)b * 16) * NCg + c) * 256;
        #pragma unroll
        for (int nt = 0; nt < 4; ++nt) {
            int d = lm + 16 * nt;
            float iv[4];
            #pragma unroll
            for (int a = 0; a < 4; ++a) iv[a] = ir0[a * 64 + d];
            #pragma unroll
            for (int r = 0; r < 4; ++r) {
                int i = rowC + r;
                float add = 0.0f;
                #pragma unroll
                for (int a = 0; a < 4; ++a) add += (ip4[a] == i) ? iv[a] : 0.0f;
                hreg[nt * 4 + r] = h0c[(size_t)i * 64 + d] + add;
            }
        }
    }
    // temp write h_in0 (bf16, [i][d]) into hidA region for transpose build
    #pragma unroll
    for (int nt = 0; nt < 4; ++nt)
        #pragma unroll
        for (int r = 0; r < 4; ++r)
            *p16_64(hidA_s, rowC + r, lm + 16 * nt) = bfr(hreg[nt * 4 + r]);
    __syncthreads();
    {   // hinT = h_in0^T
        int d = tid >> 2, q = tid & 3;
        #pragma unroll
        for (int k = 0; k < 16; k += 2) {
            int col = 16 * q + k;
            st32_64(hinT_s, d, col,
                    pack2(bf2f(*p16_64(hidA_s, col, d)),
                          bf2f(*p16_64(hidA_s, col + 1, d))));
        }
    }
    __syncthreads();

    const f32x4 zf = {0.f, 0.f, 0.f, 0.f};

    #pragma unroll 1
    for (int t = 0; t < 16; ++t) {
        int go = 0; asm volatile("" : "+v"(go));   // launder: keep L2 streams per-step

        // ==== P2: m1 = (wpow*W0 + heb) @ h_in ; write m1 -> mh_s ====
        f32x4 acc2[4] = {zf, zf, zf, zf};
        {
            bf16x8 w0lo = *(const bf16x8*)(w0p + go);
            bf16x8 w0hi = *(const bf16x8*)(w0p + 8 + go);
            bf16x8 hb0 = ld64(heb_s, rowA, kb0);
            bf16x8 hb1 = ld64(heb_s, rowA, kb0 + 64);
            bf16x8 a0, a1;
            #pragma unroll
            for (int jj = 0; jj < 8; ++jj) {
                a0[jj] = bfr(fmaf(wpowA, bf2f(w0lo[jj]), bf2f(hb0[jj])));
                a1[jj] = bfr(fmaf(wpowA, bf2f(w0hi[jj]), bf2f(hb1[jj])));
            }
            #pragma unroll
            for (int nt = 0; nt < 4; ++nt) {
                bf16x8 bb0 = ld64(hinT_s, lm + 16 * nt, kb0);
                bf16x8 bb1 = ld64(hinT_s, lm + 16 * nt, kb0 + 64);
                acc2[nt] = MFMA(a0, bb0, acc2[nt]);
                acc2[nt] = MFMA(a1, bb1, acc2[nt]);
            }
        }
        #pragma unroll
        for (int nt = 0; nt < 4; ++nt)
            #pragma unroll
            for (int r = 0; r < 4; ++r)
                *p16_64(mh_s, rowC + r, lm + 16 * nt) = bfr(acc2[nt][r]);
        __syncthreads();                                  // BA: m1 handoff

        // ==== P3a: hid = tanh(w1 @ m1^T + b1) -> hidA (no alias, write direct) ====
        #pragma unroll
        for (int mt = 0; mt < 2; ++mt) {
            bf16x8 awf0 = *(const bf16x8*)(w1b + ((32 * Wv + 16 * mt + lm) << 6) + 8 * g + go);
            bf16x8 awf1 = *(const bf16x8*)(w1b + ((32 * Wv + 16 * mt + lm) << 6) + 8 * g + 32 + go);
            float4 b1f = *(const float4*)(b1 + 32 * Wv + 16 * mt + 4 * g + go);
            float b1a[4] = {b1f.x, b1f.y, b1f.z, b1f.w};
            #pragma unroll
            for (int nt = 0; nt < 4; ++nt) {
                f32x4 a3 = zf;
                a3 = MFMA(awf0, ld64(mh_s, lm + 16 * nt, kb0),      a3);
                a3 = MFMA(awf1, ld64(mh_s, lm + 16 * nt, kb0 + 64), a3);
                float v0 = tanh_f(a3[0] + b1a[0]);
                float v1 = tanh_f(a3[1] + b1a[1]);
                float v2 = tanh_f(a3[2] + b1a[2]);
                float v3 = tanh_f(a3[3] + b1a[3]);
                st32_128(hidA_s, lm + 16 * nt, 32 * Wv + 16 * mt + 4 * g + 0, pack2(v0, v1));
                st32_128(hidA_s, lm + 16 * nt, 32 * Wv + 16 * mt + 4 * g + 2, pack2(v2, v3));
            }
        }
        __syncthreads();                                  // BB: hid handoff (m1 reads done)

        // ==== P3b: m2 = hid @ w2^T ====
        f32x4 accB[4] = {zf, zf, zf, zf};
        {
            bf16x8 ah[4];
            #pragma unroll
            for (int kt = 0; kt < 4; ++kt)
                ah[kt] = ld128(hidA_s, 16 * Wv + lm, kb0 + 64 * kt);
            #pragma unroll
            for (int kt = 0; kt < 4; ++kt)
                #pragma unroll
                for (int nt = 0; nt < 4; ++nt) {
                    const short* w2r = w2b + ((lm + 16 * nt) << 7) + 8 * g + 32 * kt + go;
                    bf16x8 bb = *(const bf16x8*)w2r;
                    accB[nt] = MFMA(ah[kt], bb, accB[nt]);
                }
        }

        // ==== P5: gated update in regs; scatter next inj; write hnA + hinT ====
        {
            int tn = (t < 15) ? t + 1 : 15;
            const float* ir = inj + (((size_t)(b * 16 + tn)) * NCg + c) * 256;
            bf16x8 nbv0 = *(const bf16x8*)(nbp + go);
            bf16x8 nbv1 = *(const bf16x8*)(nbp + 8 + go);
            float4 gf = *(const float4*)(gp + go);
            float giv[4] = {gf.x, gf.y, gf.z, gf.w};
            #pragma unroll
            for (int nt = 0; nt < 4; ++nt) {
                int d = lm + 16 * nt;
                float iv[4];
                #pragma unroll
                for (int a = 0; a < 4; ++a) iv[a] = ir[a * 64 + d];
                float hv[4];
                #pragma unroll
                for (int r = 0; r < 4; ++r) {
                    int i = rowC + r;
                    float nb = bf2f(nt < 2 ? nbv0[nt * 4 + r] : nbv1[(nt - 2) * 4 + r]);
                    float tv = tanh_f(accB[nt][r] + nb);
                    hv[r] = (1.0f - giv[r]) * hreg[nt * 4 + r] + giv[r] * tv;
                    *p16_64(mh_s, i, d) = bfr(hv[r]);           // hnA
                    float add = 0.0f;
                    #pragma unroll
                    for (int a = 0; a < 4; ++a) add += (ip4[a] == i) ? iv[a] : 0.0f;
                    hreg[nt * 4 + r] = hv[r] + add;              // h_in(t+1)
                }
                st32_64(hinT_s, d, rowC,     pack2(hreg[nt * 4 + 0], hreg[nt * 4 + 1]));
                st32_64(hinT_s, d, rowC + 2, pack2(hreg[nt * 4 + 2], hreg[nt * 4 + 3]));
            }
        }
        __syncthreads();                                  // BD: hnA handoff

        // ==== P6: hebbian outer product + readout (from hnA) ====
        f32x4 acc6[4] = {zf, zf, zf, zf};
        {
            bf16x8 ha0 = ld64(mh_s, rowA, kb0);
            bf16x8 ha1 = ld64(mh_s, rowA, kb0 + 64);
            #pragma unroll
            for (int nt = 0; nt < 4; ++nt) {
                bf16x8 bb0 = ld64(mh_s, lm + 16 * nt, kb0);
                bf16x8 bb1 = ld64(mh_s, lm + 16 * nt, kb0 + 64);
                acc6[nt] = MFMA(ha0, bb0, acc6[nt]);
                acc6[nt] = MFMA(ha1, bb1, acc6[nt]);
            }
        }
        if (tid < 64) {
            float ro = 0.125f * (bf2f(*p16_64(mh_s, op4[0], tid)) +
                                 bf2f(*p16_64(mh_s, op4[1], tid)) +
                                 bf2f(*p16_64(mh_s, op4[2], tid)) +
                                 bf2f(*p16_64(mh_s, op4[3], tid)));
            out[(((size_t)b * 16 + t) * NCg + c) * 64 + tid] = ro;
        }
        {
            float4 hf = *(const float4*)(hgp + go);
            float hgv[4] = {hf.x, hf.y, hf.z, hf.w};
            #pragma unroll
            for (int nt = 0; nt < 4; ++nt)
                #pragma unroll
                for (int r = 0; r < 4; ++r) {
                    int i = rowC + r, j = lm + 16 * nt;
                    short* hb = p16_64(heb_s, i, j);
                    float nv = (1.0f - hgv[r]) * bf2f(*hb) + hgv[r] * (acc6[nt][r] * 0.015625f);
                    *hb = (j == i) ? (short)0 : bfr(nv);
                }
        }
        wpowA *= wdecA;
        __syncthreads();                                  // BE: heb + mh_s recycle
    }
}

} // namespace

extern "C" void kernel_launch(void* const* d_in, const int* in_sizes, int n_in,
                              void* d_out, int out_size, void* d_ws, size_t ws_size,
                              hipStream_t stream) {
    (void)in_sizes; (void)n_in; (void)out_size; (void)ws_size;
    const float* x    = (const float*)d_in[0];
    const float* h0   = (const float*)d_in[1];
    const float* W0   = (const float*)d_in[2];
    const float* heb0 = (const float*)d_in[3];
    const float* nid  = (const float*)d_in[4];
    const float* w1   = (const float*)d_in[5];
    const float* b1   = (const float*)d_in[6];
    const float* w2   = (const float*)d_in[7];
    const float* b2   = (const float*)d_in[8];
    const float* injw = (const float*)d_in[9];
    const float* injb = (const float*)d_in[10];
    const float* wdl  = (const float*)d_in[11];
    const float* dgl  = (const float*)d_in[12];
    const float* hdl  = (const float*)d_in[13];
    const int*   ip   = (const int*)d_in[14];
    const int*   op   = (const int*)d_in[15];
    float* out = (float*)d_out;

    char* ws = (char*)d_ws;
    short* w2b = (short*)(ws + 0);              // 16 KB
    short* w1b = (short*)(ws + 16384);          // 16 KB
    float* gt  = (float*)(ws + 32768);          // 32 KB
    float* hgt = (float*)(ws + 65536);          // 32 KB
    short* nbt = (short*)(ws + 98304);          // 1 MB
    short* w0t = (short*)(ws + 1146880);        // 8 MB
    float* inj = (float*)(ws + 9535488);        // 16 MB

    cvt_w12<<<dim3(64), dim3(256), 0, stream>>>(w2, w1, w2b, w1b);
    build_tables<<<dim3(1024), dim3(256), 0, stream>>>(W0, nid, b2, dgl, hdl,
                                                       w0t, nbt, gt, hgt);
    inj_gemm<<<dim3(128), dim3(256), 0, stream>>>(x, injw, injb, inj);
    memgraph_mfma<<<dim3(8 * NCg), dim3(256), 0, stream>>>(
        inj, h0, heb0, w0t, nbt, gt, hgt, w1b, b1, w2b,
        wdl, ip, op, out);
}

// Round 13
// 383.382 us; speedup vs baseline: 1.3969x; 1.3296x over previous
//
#include <hip/hip_runtime.h>
#include <math.h>

namespace {

typedef __attribute__((ext_vector_type(8))) short bf16x8;
typedef __attribute__((ext_vector_type(4))) float f32x4;

constexpr int NCg = 128;

// ---- scalar helpers ----
__device__ inline short bfr(float f) {            // fp32 -> bf16 RNE
    unsigned u = __float_as_uint(f);
    unsigned r = (u + 0x7fffu + ((u >> 16) & 1u)) >> 16;
    return (short)r;
}
__device__ inline float bf2f(short s) {
    return __uint_as_float(((unsigned)(unsigned short)s) << 16);
}
__device__ inline unsigned pack2(float a, float b) {
    return (unsigned)(unsigned short)bfr(a) | ((unsigned)(unsigned short)bfr(b) << 16);
}
__device__ inline float tanh_f(float x) {         // 1 - 2/(e^{2x}+1)
    float t = __builtin_amdgcn_exp2f(x * 2.8853900817779268f);
    return 1.0f - 2.0f * __builtin_amdgcn_rcpf(t + 1.0f);
}
__device__ inline float sig05(float x) { return 0.5f / (1.0f + expf(-x)); }

// ---- swizzled LDS accessors (byte ^= (row&7)<<4) ----
__device__ inline bf16x8 ld64(const short* base, int row, int kbyte) {   // bf16 pitch 64
    int byte = (row << 7) + kbyte; byte ^= (row & 7) << 4;
    return *(const bf16x8*)((const char*)base + byte);
}
__device__ inline bf16x8 ld128(const short* base, int row, int kbyte) {  // bf16 pitch 128
    int byte = (row << 8) + kbyte; byte ^= (row & 7) << 4;
    return *(const bf16x8*)((const char*)base + byte);
}
__device__ inline short* p16_64(short* base, int row, int col) {
    int byte = (row << 7) + (col << 1); byte ^= (row & 7) << 4;
    return (short*)((char*)base + byte);
}
__device__ inline unsigned long long ldnb(const short* base, int row, int colbyte) {
    int byte = (row << 7) + colbyte; byte ^= (row & 7) << 4;   // colbyte 8-aligned
    return *(const unsigned long long*)((const char*)base + byte);
}
__device__ inline void st32_64(short* base, int row, int col, unsigned v) { // col even
    int byte = (row << 7) + (col << 1); byte ^= (row & 7) << 4;
    *(unsigned*)((char*)base + byte) = v;
}
__device__ inline void st32_128(short* base, int row, int col, unsigned v) { // col even
    int byte = (row << 8) + (col << 1); byte ^= (row & 7) << 4;
    *(unsigned*)((char*)base + byte) = v;
}
#define MFMA(a,b,c) __builtin_amdgcn_mfma_f32_16x16x32_bf16(a, b, c, 0, 0, 0)
#define PIN(v) asm volatile("" : "+v"(v))

// init: w2 [64][128] and w1 [128][64] fp32 -> bf16 tables in ws
__global__ void cvt_w12(const float* __restrict__ w2, const float* __restrict__ w1,
                        short* __restrict__ w2b, short* __restrict__ w1b) {
    int e = blockIdx.x * 256 + threadIdx.x;   // 64 blocks -> 16384
    if (e < 8192) w2b[e] = bfr(w2[e]);
    else          w1b[e - 8192] = bfr(w1[e - 8192]);
}

// init: inj[bt,c,p] = injb[c,p] + x[bt,c,:] . injw[c,p,:]   (exact fp32)
__global__ __launch_bounds__(256) void inj_gemm(
    const float* __restrict__ x,     // [128 bt][128 c][64]
    const float* __restrict__ injw,  // [c][256][64]
    const float* __restrict__ injb,  // [c][256]
    float* __restrict__ inj)         // [bt][c][256]
{
    const int c = blockIdx.x;        // 128
    const int p = threadIdx.x;       // 256
    float w[64];
    const float* wr = injw + ((size_t)c * 256 + p) * 64;
    #pragma unroll
    for (int k = 0; k < 64; k += 4) {
        float4 v = *(const float4*)(wr + k);
        w[k] = v.x; w[k+1] = v.y; w[k+2] = v.z; w[k+3] = v.w;
    }
    const float bias = injb[c * 256 + p];
    __shared__ float xs[16][64];
    #pragma unroll 1
    for (int chunk = 0; chunk < 8; ++chunk) {
        const int bt0 = chunk * 16;
        {
            int e = threadIdx.x * 4;
            *(float4*)&xs[e >> 6][e & 63] =
                *(const float4*)(x + ((size_t)(bt0 + (e >> 6)) * NCg + c) * 64 + (e & 63));
        }
        __syncthreads();
        #pragma unroll 1
        for (int r = 0; r < 16; ++r) {
            float acc = bias;
            #pragma unroll
            for (int k = 0; k < 64; ++k) acc = fmaf(w[k], xs[r][k], acc);
            inj[((size_t)(bt0 + r) * NCg + c) * 256 + p] = acc;
        }
        __syncthreads();
    }
}

__global__ __launch_bounds__(256, 3) void memgraph_mfma(
    const float* __restrict__ inj,    const float* __restrict__ h0,
    const float* __restrict__ W0,     const float* __restrict__ heb0,
    const float* __restrict__ nid,    const short* __restrict__ w1b,
    const float* __restrict__ b1,     const short* __restrict__ w2b,
    const float* __restrict__ b2,     const float* __restrict__ wdl,
    const float* __restrict__ dgl,    const float* __restrict__ hdl,
    const int*  __restrict__ iport,   const int*  __restrict__ oport,
    float* __restrict__ out)
{
    __shared__ short heb_s[4096];                                 //  8 KB
    __shared__ short hinT_s[4096];                                //  8 KB  h_in^T
    __shared__ short mh_s[4096];                                  //  8 KB  m1 / h_new
    __shared__ short nbT_s[4096];                                 //  8 KB  nb^T[d][i]
    __shared__ short hidA_s[8192] __attribute__((aligned(16)));   // 16 KB  hid (pitch 128)
    // total 49152 B -> 3 blocks/CU (matches the (256,3) register budget)

    const int bc  = blockIdx.x;
    const int b   = bc >> 7;
    const int c   = bc & (NCg - 1);
    const int tid = threadIdx.x;
    const int Wv  = tid >> 6;          // wave 0..3
    const int l   = tid & 63;
    const int g   = l >> 4;
    const int lm  = l & 15;
    const int rowC = 16 * Wv + 4 * g;  // C-frag row base (+reg r)
    const int rowA = 16 * Wv + lm;     // A-frag row
    const int kb0  = 16 * g;           // fragment k-byte base

    const size_t cellBase = (size_t)bc;

    // ---- stage hebbian ----
    const float* hb0p = heb0 + cellBase * 4096;
    #pragma unroll
    for (int u = 0; u < 16; ++u) {
        int e = tid + 256 * u;
        *p16_64(heb_s, e >> 6, e & 63) = bfr(hb0p[e]);
    }

    // ---- pinned private invariants: w0a[16] + gi/hg[8] + wdec = 25 regs ----
    float gi4[4], hg4[4], w0a[16];
    #pragma unroll
    for (int r = 0; r < 4; ++r) {
        gi4[r] = sig05(dgl[c * 64 + rowC + r]);
        hg4[r] = sig05(hdl[c * 64 + rowC + r]);
    }
    float wdecA = 1.0f - sig05(wdl[c * 64 + rowA]);
    float wpowA = 1.0f;
    {   // W0 A-layout slice (private per bc -> registers, NOT an L2 stream)
        const float* w0row = W0 + cellBase * 4096 + (size_t)rowA * 64;
        #pragma unroll
        for (int jj = 0; jj < 8; ++jj) {
            w0a[jj]     = w0row[8 * g + jj];
            w0a[8 + jj] = w0row[32 + 8 * g + jj];
        }
    }
    #pragma unroll
    for (int k = 0; k < 16; ++k) PIN(w0a[k]);
    #pragma unroll
    for (int k = 0; k < 4; ++k)  { PIN(gi4[k]); PIN(hg4[k]); }
    PIN(wdecA);

    // nbT -> LDS: nbT[d][i] = b2[d] + nid[c][i][d]  (per-c, shared: keep off regs)
    #pragma unroll
    for (int nt = 0; nt < 4; ++nt)
        #pragma unroll
        for (int r = 0; r < 4; ++r) {
            int d = lm + 16 * nt, i = rowC + r;
            *p16_64(nbT_s, d, i) = bfr(b2[d] + nid[((size_t)c * 64 + i) * 64 + d]);
        }

    int ip4[4], op4[4];
    #pragma unroll
    for (int a = 0; a < 4; ++a) { ip4[a] = iport[c * 4 + a]; op4[a] = oport[c * 4 + a]; }

    // ---- h_in state in registers: hreg[nt*4+r] = h_in[rowC+r][lm+16nt] (fp32) ----
    float hreg[16];
    {
        const float* h0c = h0 + cellBase * 4096;
        const float* ir0 = inj + (((size_t)b * 16) * NCg + c) * 256 + l;
        float injv0[4];
        #pragma unroll
        for (int a = 0; a < 4; ++a) injv0[a] = ir0[a * 64];   // coalesced, lane l = dim l
        #pragma unroll
        for (int nt = 0; nt < 4; ++nt) {
            int d = lm + 16 * nt;
            float iv[4];
            #pragma unroll
            for (int a = 0; a < 4; ++a) iv[a] = __shfl(injv0[a], d);
            #pragma unroll
            for (int r = 0; r < 4; ++r) {
                int i = rowC + r;
                float add = 0.0f;
                #pragma unroll
                for (int a = 0; a < 4; ++a) add += (ip4[a] == i) ? iv[a] : 0.0f;
                hreg[nt * 4 + r] = h0c[(size_t)i * 64 + d] + add;
            }
        }
    }
    // temp write h_in0 (bf16, [i][d], pitch-64) into hidA region for transpose build
    #pragma unroll
    for (int nt = 0; nt < 4; ++nt)
        #pragma unroll
        for (int r = 0; r < 4; ++r)
            *p16_64(hidA_s, rowC + r, lm + 16 * nt) = bfr(hreg[nt * 4 + r]);
    __syncthreads();
    {   // hinT = h_in0^T
        int d = tid >> 2, q = tid & 3;
        #pragma unroll
        for (int k = 0; k < 16; k += 2) {
            int col = 16 * q + k;
            st32_64(hinT_s, d, col,
                    pack2(bf2f(*p16_64(hidA_s, col, d)),
                          bf2f(*p16_64(hidA_s, col + 1, d))));
        }
    }
    __syncthreads();

    const f32x4 zf = {0.f, 0.f, 0.f, 0.f};

    #pragma unroll 1
    for (int t = 0; t < 16; ++t) {
        int go = 0; asm volatile("" : "+v"(go));   // launder SHARED L2 streams per-step

        // ==== P2: m1 = (wpow*W0 + heb) @ h_in ; A from pinned W0 + LDS heb ====
        f32x4 acc2[4] = {zf, zf, zf, zf};
        {
            bf16x8 hb0 = ld64(heb_s, rowA, kb0);
            bf16x8 hb1 = ld64(heb_s, rowA, kb0 + 64);
            bf16x8 a0, a1;
            #pragma unroll
            for (int jj = 0; jj < 8; ++jj) {
                a0[jj] = bfr(fmaf(wpowA, w0a[jj],     bf2f(hb0[jj])));
                a1[jj] = bfr(fmaf(wpowA, w0a[8 + jj], bf2f(hb1[jj])));
            }
            #pragma unroll
            for (int nt = 0; nt < 4; ++nt) {
                bf16x8 bb0 = ld64(hinT_s, lm + 16 * nt, kb0);
                bf16x8 bb1 = ld64(hinT_s, lm + 16 * nt, kb0 + 64);
                acc2[nt] = MFMA(a0, bb0, acc2[nt]);
                acc2[nt] = MFMA(a1, bb1, acc2[nt]);
            }
        }
        #pragma unroll
        for (int nt = 0; nt < 4; ++nt)
            #pragma unroll
            for (int r = 0; r < 4; ++r)
                *p16_64(mh_s, rowC + r, lm + 16 * nt) = bfr(acc2[nt][r]);
        __syncthreads();                                  // BA: m1 handoff

        // coalesced inj prefetch for this step's P5 (inj of t+1)
        float injv[4];
        {
            int tn = (t < 15) ? t + 1 : 15;
            const float* ir = inj + (((size_t)(b * 16 + tn)) * NCg + c) * 256 + l;
            #pragma unroll
            for (int a = 0; a < 4; ++a) injv[a] = ir[a * 64];
        }

        // ==== P3a: hid = tanh(w1 @ m1^T + b1) -> hidA (w1b/b1 shared L2 streams) ====
        #pragma unroll
        for (int mt = 0; mt < 2; ++mt) {
            bf16x8 awf0 = *(const bf16x8*)(w1b + ((32 * Wv + 16 * mt + lm) << 6) + 8 * g + go);
            bf16x8 awf1 = *(const bf16x8*)(w1b + ((32 * Wv + 16 * mt + lm) << 6) + 8 * g + 32 + go);
            float4 b1f = *(const float4*)(b1 + 32 * Wv + 16 * mt + 4 * g + go);
            float b1a[4] = {b1f.x, b1f.y, b1f.z, b1f.w};
            #pragma unroll
            for (int nt = 0; nt < 4; ++nt) {
                f32x4 a3 = zf;
                a3 = MFMA(awf0, ld64(mh_s, lm + 16 * nt, kb0),      a3);
                a3 = MFMA(awf1, ld64(mh_s, lm + 16 * nt, kb0 + 64), a3);
                float v0 = tanh_f(a3[0] + b1a[0]);
                float v1 = tanh_f(a3[1] + b1a[1]);
                float v2 = tanh_f(a3[2] + b1a[2]);
                float v3 = tanh_f(a3[3] + b1a[3]);
                st32_128(hidA_s, lm + 16 * nt, 32 * Wv + 16 * mt + 4 * g + 0, pack2(v0, v1));
                st32_128(hidA_s, lm + 16 * nt, 32 * Wv + 16 * mt + 4 * g + 2, pack2(v2, v3));
            }
        }
        __syncthreads();                                  // BB: hid handoff

        // ==== P3b: m2 = hid @ w2^T  (w2b shared L2 stream) ====
        f32x4 accB[4] = {zf, zf, zf, zf};
        {
            bf16x8 ah[4];
            #pragma unroll
            for (int kt = 0; kt < 4; ++kt)
                ah[kt] = ld128(hidA_s, 16 * Wv + lm, kb0 + 64 * kt);
            #pragma unroll
            for (int kt = 0; kt < 4; ++kt)
                #pragma unroll
                for (int nt = 0; nt < 4; ++nt) {
                    const short* w2r = w2b + ((lm + 16 * nt) << 7) + 8 * g + 32 * kt + go;
                    bf16x8 bb = *(const bf16x8*)w2r;
                    accB[nt] = MFMA(ah[kt], bb, accB[nt]);
                }
        }

        // ==== P5: gated update in regs; shuffle-scatter next inj; write hn + hinT ====
        #pragma unroll
        for (int nt = 0; nt < 4; ++nt) {
            int d = lm + 16 * nt;
            unsigned long long nbq = ldnb(nbT_s, d, rowC << 1);
            float iv[4];
            #pragma unroll
            for (int a = 0; a < 4; ++a) iv[a] = __shfl(injv[a], d);
            float hv[4];
            #pragma unroll
            for (int r = 0; r < 4; ++r) {
                int i = rowC + r;
                float nb = bf2f((short)(nbq >> (16 * r)));
                float tv = tanh_f(accB[nt][r] + nb);
                hv[r] = (1.0f - gi4[r]) * hreg[nt * 4 + r] + gi4[r] * tv;
                *p16_64(mh_s, i, d) = bfr(hv[r]);           // h_new
                float add = 0.0f;
                #pragma unroll
                for (int a = 0; a < 4; ++a) add += (ip4[a] == i) ? iv[a] : 0.0f;
                hreg[nt * 4 + r] = hv[r] + add;              // h_in(t+1)
            }
            st32_64(hinT_s, d, rowC,     pack2(hreg[nt * 4 + 0], hreg[nt * 4 + 1]));
            st32_64(hinT_s, d, rowC + 2, pack2(hreg[nt * 4 + 2], hreg[nt * 4 + 3]));
        }
        __syncthreads();                                  // BD: h_new handoff

        // ==== P6: hebbian outer product + readout (from h_new in mh_s) ====
        f32x4 acc6[4] = {zf, zf, zf, zf};
        {
            bf16x8 ha0 = ld64(mh_s, rowA, kb0);
            bf16x8 ha1 = ld64(mh_s, rowA, kb0 + 64);
            #pragma unroll
            for (int nt = 0; nt < 4; ++nt) {
                bf16x8 bb0 = ld64(mh_s, lm + 16 * nt, kb0);
                bf16x8 bb1 = ld64(mh_s, lm + 16 * nt, kb0 + 64);
                acc6[nt] = MFMA(ha0, bb0, acc6[nt]);
                acc6[nt] = MFMA(ha1, bb1, acc6[nt]);
            }
        }
        if (tid < 64) {
            float ro = 0.125f * (bf2f(*p16_64(mh_s, op4[0], tid)) +
                                 bf2f(*p16_64(mh_s, op4[1], tid)) +
                                 bf2f(*p16_64(mh_s, op4[2], tid)) +
                                 bf2f(*p16_64(mh_s, op4[3], tid)));
            out[(((size_t)b * 16 + t) * NCg + c) * 64 + tid] = ro;
        }
        #pragma unroll
        for (int nt = 0; nt < 4; ++nt)
            #pragma unroll
            for (int r = 0; r < 4; ++r) {
                int i = rowC + r, j = lm + 16 * nt;
                short* hb = p16_64(heb_s, i, j);
                float nv = (1.0f - hg4[r]) * bf2f(*hb) + hg4[r] * (acc6[nt][r] * 0.015625f);
                *hb = (j == i) ? (short)0 : bfr(nv);
            }
        wpowA *= wdecA;
        __syncthreads();                                  // BE: heb/mh/hinT recycle
    }
}

} // namespace

extern "C" void kernel_launch(void* const* d_in, const int* in_sizes, int n_in,
                              void* d_out, int out_size, void* d_ws, size_t ws_size,
                              hipStream_t stream) {
    (void)in_sizes; (void)n_in; (void)out_size; (void)ws_size;
    const float* x    = (const float*)d_in[0];
    const float* h0   = (const float*)d_in[1];
    const float* W0   = (const float*)d_in[2];
    const float* heb0 = (const float*)d_in[3];
    const float* nid  = (const float*)d_in[4];
    const float* w1   = (const float*)d_in[5];
    const float* b1   = (const float*)d_in[6];
    const float* w2   = (const float*)d_in[7];
    const float* b2   = (const float*)d_in[8];
    const float* injw = (const float*)d_in[9];
    const float* injb = (const float*)d_in[10];
    const float* wdl  = (const float*)d_in[11];
    const float* dgl  = (const float*)d_in[12];
    const float* hdl  = (const float*)d_in[13];
    const int*   ip   = (const int*)d_in[14];
    const int*   op   = (const int*)d_in[15];
    float* out = (float*)d_out;

    char* ws = (char*)d_ws;
    short* w2b = (short*)(ws + 0);              // 16 KB
    short* w1b = (short*)(ws + 16384);          // 16 KB
    float* inj = (float*)(ws + 65536);          // 16 MB fp32 [bt][c][256]

    cvt_w12<<<dim3(64), dim3(256), 0, stream>>>(w2, w1, w2b, w1b);
    inj_gemm<<<dim3(128), dim3(256), 0, stream>>>(x, injw, injb, inj);
    memgraph_mfma<<<dim3(8 * NCg), dim3(256), 0, stream>>>(
        inj, h0, W0, heb0, nid, w1b, b1, w2b, b2,
        wdl, dgl, hdl, ip, op, out);
}